// Round 4
// baseline (719.651 us; speedup 1.0000x reference)
//
#include <hip/hip_runtime.h>
#include <hip/hip_cooperative_groups.h>

namespace cg = cooperative_groups;

#define BATCH 128
#define SENS 128
#define UNITS 512
#define MOTOR 64
#define UNFOLDS 6
#define L2E 1.442695040888963f
#define EPS 1e-8f

#define BT 8      // batches per block (register-blocked)
#define UT 8      // units per block
#define STP 12    // transposed LDS row stride (8 data + 4 pad, conflict-free)

// ===========================================================================
// Fused cooperative kernel: fold -> sensory -> 6 unfolds with grid.sync().
// Grid MUST be 1024 blocks x 256 threads (4 blocks/CU co-resident).
// ===========================================================================
__global__ __launch_bounds__(256, 4) void ltc_fused_kernel(
    const float* __restrict__ inputs, const float* __restrict__ state,
    const float* __restrict__ gleak, const float* __restrict__ vleak,
    const float* __restrict__ cm,
    const float* __restrict__ sigma, const float* __restrict__ mu,
    const float* __restrict__ w, const float* __restrict__ erev,
    const float* __restrict__ mask,
    const float* __restrict__ ssig, const float* __restrict__ smu,
    const float* __restrict__ sw, const float* __restrict__ serev,
    const float* __restrict__ smask,
    const float* __restrict__ input_w, const float* __restrict__ input_b,
    const float* __restrict__ output_w, const float* __restrict__ output_b,
    float4* __restrict__ pw4,
    float* __restrict__ stA, float* __restrict__ stB,
    float* __restrict__ out)
{
    __shared__ __align__(16) float stT[UNITS][STP];  // transposed [v][b] tile
    __shared__ float2 red[4][BT][UT];
    __shared__ float2 sens[BT][UT];

    cg::grid_group grid = cg::this_grid();
    int tid = threadIdx.x;

    // ---- Phase A: fold recurrent weights (exactly 1 elem/thread) ----
    {
        int i = blockIdx.x * 256 + tid;          // grid*block == UNITS*UNITS
        float sg = sigma[i] * L2E;
        float wmv = w[i] * mask[i];
        float4 q;
        q.x = sg; q.y = mu[i] * sg; q.z = wmv; q.w = wmv * erev[i];
        pw4[i] = q;
    }

    // block tile mapping (bijective XCD chunking: 1024 % 8 == 0)
    int logical = (blockIdx.x & 7) * 128 + (blockIdx.x >> 3);
    int ut = logical >> 4;                       // 0..63
    int bt = logical & 15;                       // 0..15
    int b0 = bt * BT;
    int u0 = ut * UT;

    int ul  = tid & 7;
    int grp = tid >> 3;                          // 0..31 (s-group / v-group)
    int u = u0 + ul;
    int lane = tid & 63;
    int wid = tid >> 6;

    // ---- Phase B: sensory accumulators -> sens[][] (LDS, block-private) ----
    {
        // stage x transposed into stT rows 0..127, affine applied on the fly
        int bl = tid & 7;
        int s4 = tid >> 3;                       // 0..31
        const float4* xv = (const float4*)(inputs + (size_t)(b0 + bl) * SENS);
        float4 t4 = xv[s4];
        float4 iw = ((const float4*)input_w)[s4];
        float4 ib = ((const float4*)input_b)[s4];
        stT[s4 * 4 + 0][bl] = __builtin_fmaf(t4.x, iw.x, ib.x);
        stT[s4 * 4 + 1][bl] = __builtin_fmaf(t4.y, iw.y, ib.y);
        stT[s4 * 4 + 2][bl] = __builtin_fmaf(t4.z, iw.z, ib.z);
        stT[s4 * 4 + 3][bl] = __builtin_fmaf(t4.w, iw.w, ib.w);
        __syncthreads();

        float num[BT], den[BT];
        #pragma unroll
        for (int b = 0; b < BT; ++b) { num[b] = 0.f; den[b] = 0.f; }

        #pragma unroll
        for (int i = 0; i < SENS / 32; ++i) {    // s = grp + 32*i
            int s = grp + 32 * i;
            size_t k = (size_t)s * UNITS + u;
            float sgv = ssig[k] * L2E;
            float mt  = smu[k] * sgv;
            float wmv = sw[k] * smask[k];
            float wev = wmv * serev[k];
            const float4* sp = (const float4*)&stT[s][0];
            float4 xa = sp[0];
            float4 xb = sp[1];
            float sarr[8] = {xa.x, xa.y, xa.z, xa.w, xb.x, xb.y, xb.z, xb.w};
            #pragma unroll
            for (int b = 0; b < BT; ++b) {
                float t = __builtin_fmaf(-sarr[b], sgv, mt);
                float e = __builtin_amdgcn_exp2f(t);
                float sg = __builtin_amdgcn_rcpf(1.0f + e);
                num[b] = __builtin_fmaf(wev, sg, num[b]);
                den[b] = __builtin_fmaf(wmv, sg, den[b]);
            }
        }
        #pragma unroll
        for (int b = 0; b < BT; ++b) {
            #pragma unroll
            for (int m = 8; m <= 32; m <<= 1) {
                num[b] += __shfl_xor(num[b], m, 64);
                den[b] += __shfl_xor(den[b], m, 64);
            }
        }
        if (lane < 8) {
            #pragma unroll
            for (int b = 0; b < BT; ++b)
                red[wid][b][lane] = make_float2(num[b], den[b]);
        }
        __syncthreads();
        if (tid < 64) {
            int uu = tid & 7;
            int bb = tid >> 3;
            float n = 0.f, d = 0.f;
            #pragma unroll
            for (int k = 0; k < 4; ++k) {
                float2 v = red[k][bb][uu];
                n += v.x; d += v.y;
            }
            sens[bb][uu] = make_float2(n, d);
        }
    }

    // epilogue constants (thread<64 mapping is fixed across unfolds)
    float eg = 0.f, evl = 0.f, ec = 0.f, eow = 0.f, eob = 0.f;
    if (tid < 64) {
        int uu = tid & 7;
        int gu = u0 + uu;
        eg  = gleak[gu];
        evl = vleak[gu];
        ec  = cm[gu] * (float)UNFOLDS;
        if (gu < MOTOR) { eow = output_w[gu]; eob = output_b[gu]; }
    }

    grid.sync();   // pw4 complete everywhere; sens/epilogue ready per-block

    float* stateOut = out + BATCH * MOTOR;

    for (int t = 0; t < UNFOLDS; ++t) {
        const float* src;
        float* dst;
        if (t == 0)      src = state;
        else if (t & 1)  src = stA;
        else             src = stB;
        if (t == UNFOLDS - 1) dst = stateOut;
        else if (t & 1)       dst = stB;
        else                  dst = stA;

        // stage state rows b0..b0+7 transposed into stT
        {
            const float4* sv = (const float4*)(src + (size_t)b0 * UNITS);
            int bl = tid & 7;
            int v4b = tid >> 3;                  // 0..31
            #pragma unroll
            for (int k = 0; k < 4; ++k) {
                int v4 = v4b + 32 * k;           // 0..127
                float4 t4 = sv[bl * (UNITS / 4) + v4];
                stT[v4 * 4 + 0][bl] = t4.x;
                stT[v4 * 4 + 1][bl] = t4.y;
                stT[v4 * 4 + 2][bl] = t4.z;
                stT[v4 * 4 + 3][bl] = t4.w;
            }
        }
        __syncthreads();

        float num[BT], den[BT];
        #pragma unroll
        for (int b = 0; b < BT; ++b) { num[b] = 0.f; den[b] = 0.f; }

        const float4* pv = pw4 + (size_t)grp * UNITS + u;
        const float* srow = &stT[grp][0];
        #pragma unroll 4
        for (int i = 0; i < UNITS / 32; ++i) {   // v = grp + 32*i
            float4 q = pv[0];
            pv += 32 * UNITS;
            const float4* sp = (const float4*)srow;
            float4 xa = sp[0];
            float4 xb = sp[1];
            srow += 32 * STP;
            float sarr[8] = {xa.x, xa.y, xa.z, xa.w, xb.x, xb.y, xb.z, xb.w};
            #pragma unroll
            for (int b = 0; b < BT; ++b) {
                float tt = __builtin_fmaf(-sarr[b], q.x, q.y);
                float e = __builtin_amdgcn_exp2f(tt);
                float sg = __builtin_amdgcn_rcpf(1.0f + e);
                num[b] = __builtin_fmaf(q.w, sg, num[b]);
                den[b] = __builtin_fmaf(q.z, sg, den[b]);
            }
        }

        #pragma unroll
        for (int b = 0; b < BT; ++b) {
            #pragma unroll
            for (int m = 8; m <= 32; m <<= 1) {
                num[b] += __shfl_xor(num[b], m, 64);
                den[b] += __shfl_xor(den[b], m, 64);
            }
        }
        if (lane < 8) {
            #pragma unroll
            for (int b = 0; b < BT; ++b)
                red[wid][b][lane] = make_float2(num[b], den[b]);
        }
        __syncthreads();
        if (tid < 64) {
            int uu = tid & 7;
            int bb = tid >> 3;
            float n = 0.f, d = 0.f;
            #pragma unroll
            for (int k = 0; k < 4; ++k) {
                float2 v = red[k][bb][uu];
                n += v.x; d += v.y;
            }
            int gu = u0 + uu;
            int gb = b0 + bb;
            float vpre = stT[gu][bb];
            float2 sv2 = sens[bb][uu];
            float numer = __builtin_fmaf(ec, vpre,
                            __builtin_fmaf(eg, evl, sv2.x + n));
            float denom = ec + eg + sv2.y + d + EPS;
            float res = numer * __builtin_amdgcn_rcpf(denom);
            dst[gb * UNITS + gu] = res;
            if (t == UNFOLDS - 1 && gu < MOTOR) {
                out[gb * MOTOR + gu] = __builtin_fmaf(res, eow, eob);
            }
        }
        if (t < UNFOLDS - 1) grid.sync();
    }
}

// ===========================================================================
// Fallback path (round-3 kernels) in case cooperative launch is unavailable.
// ===========================================================================
__global__ __launch_bounds__(256) void fold_kernel(
    const float* __restrict__ sigma, const float* __restrict__ mu,
    const float* __restrict__ w, const float* __restrict__ erev,
    const float* __restrict__ mask,
    const float* __restrict__ ssig, const float* __restrict__ smu,
    const float* __restrict__ sw, const float* __restrict__ serev,
    const float* __restrict__ smask,
    const float* __restrict__ inputs, const float* __restrict__ input_w,
    const float* __restrict__ input_b,
    float4* __restrict__ pw4, float4* __restrict__ ps4,
    float* __restrict__ x)
{
    int i = blockIdx.x * 256 + threadIdx.x;
    if (i < UNITS * UNITS) {
        float sg = sigma[i] * L2E;
        float wmv = w[i] * mask[i];
        float4 q;
        q.x = sg; q.y = mu[i] * sg; q.z = wmv; q.w = wmv * erev[i];
        pw4[i] = q;
    }
    if (i < SENS * UNITS) {
        float sg = ssig[i] * L2E;
        float wmv = sw[i] * smask[i];
        float4 q;
        q.x = sg; q.y = smu[i] * sg; q.z = wmv; q.w = wmv * serev[i];
        ps4[i] = q;
    }
    if (i < BATCH * SENS) {
        int s = i & (SENS - 1);
        x[i] = __builtin_fmaf(inputs[i], input_w[s], input_b[s]);
    }
}

__global__ __launch_bounds__(256, 4) void sensory_kernel(
    const float* __restrict__ x,
    const float4* __restrict__ ps4,
    float* __restrict__ wns, float* __restrict__ wds)
{
    __shared__ __align__(16) float xsT[SENS][STP];
    __shared__ float2 red[4][BT][UT];

    int phys = blockIdx.x;
    int logical = (phys & 7) * 128 + (phys >> 3);
    int ut = logical >> 4;
    int bt = logical & 15;
    int b0 = bt * BT;
    int u0 = ut * UT;

    {
        const float4* xv = (const float4*)(x + b0 * SENS);
        int bl = threadIdx.x & 7;
        int s4 = threadIdx.x >> 3;
        float4 t = xv[bl * (SENS / 4) + s4];
        xsT[s4 * 4 + 0][bl] = t.x;
        xsT[s4 * 4 + 1][bl] = t.y;
        xsT[s4 * 4 + 2][bl] = t.z;
        xsT[s4 * 4 + 3][bl] = t.w;
    }
    __syncthreads();

    int ul = threadIdx.x & 7;
    int ss = threadIdx.x >> 3;
    int u = u0 + ul;

    float num[BT], den[BT];
    #pragma unroll
    for (int b = 0; b < BT; ++b) { num[b] = 0.f; den[b] = 0.f; }

    const float4* pv = ps4 + (size_t)ss * UNITS + u;
    const float* srow = &xsT[ss][0];
    #pragma unroll
    for (int i = 0; i < SENS / 32; ++i) {
        float4 q = pv[0];
        pv += 32 * UNITS;
        const float4* sp = (const float4*)srow;
        float4 xa = sp[0];
        float4 xb = sp[1];
        srow += 32 * STP;
        float sarr[8] = {xa.x, xa.y, xa.z, xa.w, xb.x, xb.y, xb.z, xb.w};
        #pragma unroll
        for (int b = 0; b < BT; ++b) {
            float t = __builtin_fmaf(-sarr[b], q.x, q.y);
            float e = __builtin_amdgcn_exp2f(t);
            float sg = __builtin_amdgcn_rcpf(1.0f + e);
            num[b] = __builtin_fmaf(q.w, sg, num[b]);
            den[b] = __builtin_fmaf(q.z, sg, den[b]);
        }
    }
    #pragma unroll
    for (int b = 0; b < BT; ++b) {
        #pragma unroll
        for (int m = 8; m <= 32; m <<= 1) {
            num[b] += __shfl_xor(num[b], m, 64);
            den[b] += __shfl_xor(den[b], m, 64);
        }
    }
    int lane = threadIdx.x & 63;
    int wid = threadIdx.x >> 6;
    if (lane < 8) {
        #pragma unroll
        for (int b = 0; b < BT; ++b)
            red[wid][b][lane] = make_float2(num[b], den[b]);
    }
    __syncthreads();
    if (threadIdx.x < 64) {
        int uu = threadIdx.x & 7;
        int bb = threadIdx.x >> 3;
        float n = 0.f, d = 0.f;
        #pragma unroll
        for (int k = 0; k < 4; ++k) {
            float2 v = red[k][bb][uu];
            n += v.x; d += v.y;
        }
        int gidx = (b0 + bb) * UNITS + (u0 + uu);
        wns[gidx] = n;
        wds[gidx] = d;
    }
}

__global__ __launch_bounds__(256, 4) void unfold_kernel(
    const float* __restrict__ src,
    float* __restrict__ dst,
    const float4* __restrict__ pw4,
    const float* __restrict__ wns, const float* __restrict__ wds,
    const float* __restrict__ gleak, const float* __restrict__ vleak,
    const float* __restrict__ cm,
    const float* __restrict__ output_w, const float* __restrict__ output_b,
    float* __restrict__ out_motor,
    int last)
{
    __shared__ __align__(16) float stT[UNITS][STP];
    __shared__ float2 red[4][BT][UT];

    int phys = blockIdx.x;
    int logical = (phys & 7) * 128 + (phys >> 3);
    int ut = logical >> 4;
    int bt = logical & 15;
    int b0 = bt * BT;
    int u0 = ut * UT;

    {
        const float4* sv = (const float4*)(src + (size_t)b0 * UNITS);
        int bl = threadIdx.x & 7;
        int v4b = threadIdx.x >> 3;
        #pragma unroll
        for (int k = 0; k < 4; ++k) {
            int v4 = v4b + 32 * k;
            float4 t = sv[bl * (UNITS / 4) + v4];
            stT[v4 * 4 + 0][bl] = t.x;
            stT[v4 * 4 + 1][bl] = t.y;
            stT[v4 * 4 + 2][bl] = t.z;
            stT[v4 * 4 + 3][bl] = t.w;
        }
    }
    __syncthreads();

    int ul = threadIdx.x & 7;
    int vs = threadIdx.x >> 3;
    int u = u0 + ul;

    float num[BT], den[BT];
    #pragma unroll
    for (int b = 0; b < BT; ++b) { num[b] = 0.f; den[b] = 0.f; }

    const float4* pv = pw4 + (size_t)vs * UNITS + u;
    const float* srow = &stT[vs][0];
    #pragma unroll 4
    for (int i = 0; i < UNITS / 32; ++i) {
        float4 q = pv[0];
        pv += 32 * UNITS;
        const float4* sp = (const float4*)srow;
        float4 xa = sp[0];
        float4 xb = sp[1];
        srow += 32 * STP;
        float sarr[8] = {xa.x, xa.y, xa.z, xa.w, xb.x, xb.y, xb.z, xb.w};
        #pragma unroll
        for (int b = 0; b < BT; ++b) {
            float t = __builtin_fmaf(-sarr[b], q.x, q.y);
            float e = __builtin_amdgcn_exp2f(t);
            float sg = __builtin_amdgcn_rcpf(1.0f + e);
            num[b] = __builtin_fmaf(q.w, sg, num[b]);
            den[b] = __builtin_fmaf(q.z, sg, den[b]);
        }
    }
    #pragma unroll
    for (int b = 0; b < BT; ++b) {
        #pragma unroll
        for (int m = 8; m <= 32; m <<= 1) {
            num[b] += __shfl_xor(num[b], m, 64);
            den[b] += __shfl_xor(den[b], m, 64);
        }
    }
    int lane = threadIdx.x & 63;
    int wid = threadIdx.x >> 6;
    if (lane < 8) {
        #pragma unroll
        for (int b = 0; b < BT; ++b)
            red[wid][b][lane] = make_float2(num[b], den[b]);
    }
    __syncthreads();
    if (threadIdx.x < 64) {
        int uu = threadIdx.x & 7;
        int bb = threadIdx.x >> 3;
        float n = 0.f, d = 0.f;
        #pragma unroll
        for (int k = 0; k < 4; ++k) {
            float2 v = red[k][bb][uu];
            n += v.x; d += v.y;
        }
        int gu = u0 + uu;
        int gb = b0 + bb;
        float vpre = stT[gu][bb];
        float g = gleak[gu];
        float c = cm[gu] * (float)UNFOLDS;
        int gidx = gb * UNITS + gu;
        float numer = __builtin_fmaf(c, vpre,
                        __builtin_fmaf(g, vleak[gu], wns[gidx] + n));
        float denom = c + g + wds[gidx] + d + EPS;
        float res = numer * __builtin_amdgcn_rcpf(denom);
        dst[gidx] = res;
        if (last && gu < MOTOR) {
            out_motor[gb * MOTOR + gu] =
                __builtin_fmaf(res, output_w[gu], output_b[gu]);
        }
    }
}

// ===========================================================================
extern "C" void kernel_launch(void* const* d_in, const int* in_sizes, int n_in,
                              void* d_out, int out_size, void* d_ws, size_t ws_size,
                              hipStream_t stream) {
    const float* inputs   = (const float*)d_in[0];
    const float* state    = (const float*)d_in[1];
    const float* gleak    = (const float*)d_in[2];
    const float* vleak    = (const float*)d_in[3];
    const float* cm       = (const float*)d_in[4];
    const float* sigma    = (const float*)d_in[5];
    const float* mu       = (const float*)d_in[6];
    const float* w        = (const float*)d_in[7];
    const float* erev     = (const float*)d_in[8];
    const float* ssig     = (const float*)d_in[9];
    const float* smu      = (const float*)d_in[10];
    const float* sw       = (const float*)d_in[11];
    const float* serev    = (const float*)d_in[12];
    const float* input_w  = (const float*)d_in[13];
    const float* input_b  = (const float*)d_in[14];
    const float* output_w = (const float*)d_in[15];
    const float* output_b = (const float*)d_in[16];
    const float* mask     = (const float*)d_in[17];
    const float* smask    = (const float*)d_in[18];

    float* out = (float*)d_out;
    float* ws  = (float*)d_ws;

    float4* pw4 = (float4*)ws;                       // U*U float4
    float4* ps4 = (float4*)(ws + 4 * UNITS * UNITS); // S*U float4 (fallback)
    float*  x   = ws + 4 * UNITS * UNITS + 4 * SENS * UNITS;  // B*S (fallback)
    float*  wns = x + BATCH * SENS;                  // B*U (fallback)
    float*  wds = wns + BATCH * UNITS;               // B*U (fallback)
    float*  stA = wds + BATCH * UNITS;               // B*U
    float*  stB = stA + BATCH * UNITS;               // B*U

    int dev = 0;
    hipGetDevice(&dev);
    int coop = 0;
    hipDeviceGetAttribute(&coop, hipDeviceAttributeCooperativeLaunch, dev);

    hipError_t err = hipErrorUnknown;
    if (coop) {
        void* args[] = {
            (void*)&inputs, (void*)&state, (void*)&gleak, (void*)&vleak,
            (void*)&cm, (void*)&sigma, (void*)&mu, (void*)&w, (void*)&erev,
            (void*)&mask, (void*)&ssig, (void*)&smu, (void*)&sw,
            (void*)&serev, (void*)&smask, (void*)&input_w, (void*)&input_b,
            (void*)&output_w, (void*)&output_b,
            (void*)&pw4, (void*)&stA, (void*)&stB, (void*)&out
        };
        err = hipLaunchCooperativeKernel((void*)ltc_fused_kernel,
                                         dim3(1024), dim3(256),
                                         args, 0, stream);
    }
    if (err != hipSuccess) {
        // fallback: round-3 multi-launch path
        fold_kernel<<<(UNITS * UNITS + 255) / 256, 256, 0, stream>>>(
            sigma, mu, w, erev, mask, ssig, smu, sw, serev, smask,
            inputs, input_w, input_b, pw4, ps4, x);

        sensory_kernel<<<1024, 256, 0, stream>>>(x, ps4, wns, wds);

        float* state_out = out + BATCH * MOTOR;
        float* dsts[UNFOLDS] = {stA, stB, stA, stB, stA, state_out};

        const float* src = state;
        for (int t = 0; t < UNFOLDS; ++t) {
            int last = (t == UNFOLDS - 1) ? 1 : 0;
            unfold_kernel<<<1024, 256, 0, stream>>>(
                src, dsts[t], pw4, wns, wds,
                gleak, vleak, cm, output_w, output_b, out, last);
            src = dsts[t];
        }
    }
}

// Round 5
// 88.742 us; speedup vs baseline: 8.1095x; 8.1095x over previous
//
#include <hip/hip_runtime.h>

#define BATCH 128
#define SENS 128
#define UNITS 512
#define MOTOR 64
#define UNFOLDS 6
#define L2E 1.442695040888963f
#define EPS 1e-8f

#define BT 8      // batches per block (register-blocked)
#define UT 8      // units per block
#define STP 12    // LDS row stride: 48B (16B-aligned), spreads banks
#define MAXN 352  // max nonzeros per column (256 mean + >8 sigma margin)

// ===========================================================================
// Prep kernel (1024 blocks x 256):
//  - blocks < 128: compact the recurrent matrix per u-column (wave per u,
//    ballot scan over v ascending -> sorted, deterministic, no atomics).
//    entry: qvA[u][e] = {sigma*log2e, mu*sigma*log2e, w*m, w*m*erev},
//           idxA[u][e] = v;  cntA[u] = nnz.
//  - all blocks: dense sensory accumulators -> wns/wds  (8b x 8u tile,
//    8 batch-accumulators per thread, x affine applied during staging).
// ===========================================================================
__global__ __launch_bounds__(256, 4) void prep_kernel(
    const float* __restrict__ inputs, const float* __restrict__ input_w,
    const float* __restrict__ input_b,
    const float* __restrict__ ssig, const float* __restrict__ smu,
    const float* __restrict__ sw, const float* __restrict__ serev,
    const float* __restrict__ smask,
    const float* __restrict__ sigma, const float* __restrict__ mu,
    const float* __restrict__ w, const float* __restrict__ erev,
    const float* __restrict__ mask,
    float4* __restrict__ qvA, int* __restrict__ idxA, int* __restrict__ cntA,
    float* __restrict__ wns, float* __restrict__ wds)
{
    __shared__ __align__(16) float xsT[SENS][STP];
    __shared__ float2 red[4][BT][UT];

    int tid = threadIdx.x;

    // ---- recurrent compaction: wave per u column, sorted by v ----
    if (blockIdx.x < 128) {
        int wv = tid >> 6;                 // 0..3
        int lane = tid & 63;
        int u = blockIdx.x * 4 + wv;       // 0..511
        int slot = 0;
        #pragma unroll
        for (int vb = 0; vb < 8; ++vb) {
            int v = vb * 64 + lane;
            size_t k = (size_t)v * UNITS + u;
            float mv = mask[k];
            bool nz = (mv != 0.0f);
            unsigned long long bal = __ballot(nz);
            int pre = __popcll(bal & ((1ULL << lane) - 1ULL));
            int s = slot + pre;
            if (nz && s < MAXN) {
                float sg = sigma[k] * L2E;
                float wmv = w[k] * mv;
                float4 q;
                q.x = sg; q.y = mu[k] * sg; q.z = wmv; q.w = wmv * erev[k];
                qvA[(size_t)u * MAXN + s] = q;
                idxA[(size_t)u * MAXN + s] = v;
            }
            slot += __popcll(bal);
        }
        if (lane == 0) cntA[u] = (slot < MAXN) ? slot : MAXN;
    }

    // ---- sensory accumulators (all blocks) ----
    int logical = (blockIdx.x & 7) * 128 + (blockIdx.x >> 3);
    int ut = logical >> 4;                 // 0..63
    int bt = logical & 15;                 // 0..15
    int b0 = bt * BT;
    int u0 = ut * UT;

    {   // stage x transposed, affine applied on the fly
        int bl = tid & 7;
        int s4 = tid >> 3;                 // 0..31
        const float4* xv = (const float4*)(inputs + (size_t)(b0 + bl) * SENS);
        float4 t4 = xv[s4];
        float4 iw = ((const float4*)input_w)[s4];
        float4 ib = ((const float4*)input_b)[s4];
        xsT[s4 * 4 + 0][bl] = __builtin_fmaf(t4.x, iw.x, ib.x);
        xsT[s4 * 4 + 1][bl] = __builtin_fmaf(t4.y, iw.y, ib.y);
        xsT[s4 * 4 + 2][bl] = __builtin_fmaf(t4.z, iw.z, ib.z);
        xsT[s4 * 4 + 3][bl] = __builtin_fmaf(t4.w, iw.w, ib.w);
    }
    __syncthreads();

    int ul = tid & 7;
    int grp = tid >> 3;                    // 0..31
    int u = u0 + ul;

    float num[BT], den[BT];
    #pragma unroll
    for (int b = 0; b < BT; ++b) { num[b] = 0.f; den[b] = 0.f; }

    #pragma unroll
    for (int i = 0; i < SENS / 32; ++i) {  // s = grp + 32*i
        int s = grp + 32 * i;
        size_t k = (size_t)s * UNITS + u;
        float sgv = ssig[k] * L2E;
        float mt  = smu[k] * sgv;
        float wmv = sw[k] * smask[k];
        float wev = wmv * serev[k];
        const float4* sp = (const float4*)&xsT[s][0];
        float4 xa = sp[0];
        float4 xb = sp[1];
        float sarr[8] = {xa.x, xa.y, xa.z, xa.w, xb.x, xb.y, xb.z, xb.w};
        #pragma unroll
        for (int b = 0; b < BT; ++b) {
            float t = __builtin_fmaf(-sarr[b], sgv, mt);
            float e = __builtin_amdgcn_exp2f(t);
            float sg = __builtin_amdgcn_rcpf(1.0f + e);
            num[b] = __builtin_fmaf(wev, sg, num[b]);
            den[b] = __builtin_fmaf(wmv, sg, den[b]);
        }
    }
    #pragma unroll
    for (int b = 0; b < BT; ++b) {
        #pragma unroll
        for (int m = 8; m <= 32; m <<= 1) {
            num[b] += __shfl_xor(num[b], m, 64);
            den[b] += __shfl_xor(den[b], m, 64);
        }
    }
    int lane = tid & 63;
    int wid = tid >> 6;
    if (lane < 8) {
        #pragma unroll
        for (int b = 0; b < BT; ++b)
            red[wid][b][lane] = make_float2(num[b], den[b]);
    }
    __syncthreads();
    if (tid < 64) {
        int uu = tid & 7;
        int bb = tid >> 3;
        float n = 0.f, d = 0.f;
        #pragma unroll
        for (int k = 0; k < 4; ++k) {
            float2 v = red[k][bb][uu];
            n += v.x; d += v.y;
        }
        int gidx = (b0 + bb) * UNITS + (u0 + uu);
        wns[gidx] = n;
        wds[gidx] = d;
    }
}

// ===========================================================================
// Sparse unfold.  256 thr = 8 u (tid>>5) x 32 entry-lanes (tid&31); each
// thread accumulates 8 batches in registers over its u's compacted nonzero
// list (sorted by v).  State tile [v][b] in LDS; per-entry: 1 dwordx4 +
// 1 dword VMEM (L2-hot) + 2 ds_read_b128 + 8 sigmoid chains.
// ===========================================================================
__global__ __launch_bounds__(256, 4) void unfold_sparse_kernel(
    const float* __restrict__ src,     // [B,U]
    float* __restrict__ dst,           // [B,U]
    const float4* __restrict__ qvA, const int* __restrict__ idxA,
    const int* __restrict__ cntA,
    const float* __restrict__ wns, const float* __restrict__ wds,
    const float* __restrict__ gleak, const float* __restrict__ vleak,
    const float* __restrict__ cm,
    const float* __restrict__ output_w, const float* __restrict__ output_b,
    float* __restrict__ out_motor,     // [B,MOTOR]
    int last)
{
    __shared__ __align__(16) float stT[UNITS][STP];  // [v][b] tile

    int logical = (blockIdx.x & 7) * 128 + (blockIdx.x >> 3);
    int ut = logical >> 4;
    int bt = logical & 15;
    int b0 = bt * BT;
    int u0 = ut * UT;
    int tid = threadIdx.x;

    // stage state rows b0..b0+7 transposed into stT
    {
        const float4* sv = (const float4*)(src + (size_t)b0 * UNITS);
        int bl = tid & 7;
        int v4b = tid >> 3;                // 0..31
        #pragma unroll
        for (int k = 0; k < 4; ++k) {
            int v4 = v4b + 32 * k;         // 0..127
            float4 t4 = sv[bl * (UNITS / 4) + v4];
            stT[v4 * 4 + 0][bl] = t4.x;
            stT[v4 * 4 + 1][bl] = t4.y;
            stT[v4 * 4 + 2][bl] = t4.z;
            stT[v4 * 4 + 3][bl] = t4.w;
        }
    }
    __syncthreads();

    int grp = tid & 31;                    // entry lane
    int ul  = tid >> 5;                    // 0..7
    int u = u0 + ul;
    int cnt_u = cntA[u];
    const float4* qp = qvA + (size_t)u * MAXN;
    const int*    ip = idxA + (size_t)u * MAXN;

    float num[BT], den[BT];
    #pragma unroll
    for (int b = 0; b < BT; ++b) { num[b] = 0.f; den[b] = 0.f; }

    #pragma unroll 2
    for (int e = grp; e < cnt_u; e += 32) {
        float4 q = qp[e];
        int vi = ip[e];
        const float* srow = &stT[0][0] + vi * STP;
        float4 xa = ((const float4*)srow)[0];
        float4 xb = ((const float4*)srow)[1];
        float sarr[8] = {xa.x, xa.y, xa.z, xa.w, xb.x, xb.y, xb.z, xb.w};
        #pragma unroll
        for (int b = 0; b < BT; ++b) {
            float t = __builtin_fmaf(-sarr[b], q.x, q.y);  // (mu-s)*sig*l2e
            float e2 = __builtin_amdgcn_exp2f(t);
            float sg = __builtin_amdgcn_rcpf(1.0f + e2);
            num[b] = __builtin_fmaf(q.w, sg, num[b]);
            den[b] = __builtin_fmaf(q.z, sg, den[b]);
        }
    }

    // reduce across the 32 entry-lanes (lane bits 0..4; ul = bit 5 untouched)
    #pragma unroll
    for (int b = 0; b < BT; ++b) {
        #pragma unroll
        for (int m = 1; m <= 16; m <<= 1) {
            num[b] += __shfl_xor(num[b], m, 64);
            den[b] += __shfl_xor(den[b], m, 64);
        }
    }

    if (grp == 0) {
        float g  = gleak[u];
        float vl = vleak[u];
        float c  = cm[u] * (float)UNFOLDS;
        float ow = 0.f, ob = 0.f;
        if (u < MOTOR) { ow = output_w[u]; ob = output_b[u]; }
        #pragma unroll
        for (int b = 0; b < BT; ++b) {
            int gb = b0 + b;
            int gidx = gb * UNITS + u;
            float vpre = stT[u][b];
            float numer = __builtin_fmaf(c, vpre,
                            __builtin_fmaf(g, vl, wns[gidx] + num[b]));
            float denom = c + g + wds[gidx] + den[b] + EPS;
            float res = numer * __builtin_amdgcn_rcpf(denom);
            dst[gidx] = res;
            if (last && u < MOTOR) {
                out_motor[gb * MOTOR + u] = __builtin_fmaf(res, ow, ob);
            }
        }
    }
}

// ===========================================================================
extern "C" void kernel_launch(void* const* d_in, const int* in_sizes, int n_in,
                              void* d_out, int out_size, void* d_ws, size_t ws_size,
                              hipStream_t stream) {
    const float* inputs   = (const float*)d_in[0];
    const float* state    = (const float*)d_in[1];
    const float* gleak    = (const float*)d_in[2];
    const float* vleak    = (const float*)d_in[3];
    const float* cm       = (const float*)d_in[4];
    const float* sigma    = (const float*)d_in[5];
    const float* mu       = (const float*)d_in[6];
    const float* w        = (const float*)d_in[7];
    const float* erev     = (const float*)d_in[8];
    const float* ssig     = (const float*)d_in[9];
    const float* smu      = (const float*)d_in[10];
    const float* sw       = (const float*)d_in[11];
    const float* serev    = (const float*)d_in[12];
    const float* input_w  = (const float*)d_in[13];
    const float* input_b  = (const float*)d_in[14];
    const float* output_w = (const float*)d_in[15];
    const float* output_b = (const float*)d_in[16];
    const float* mask     = (const float*)d_in[17];
    const float* smask    = (const float*)d_in[18];

    float* out = (float*)d_out;
    float* ws  = (float*)d_ws;

    // ws layout (float offsets; qvA first -> 16B aligned)
    float4* qvA  = (float4*)ws;                            // 512*MAXN float4
    int*    idxA = (int*)(ws + 4 * UNITS * MAXN);          // 512*MAXN int
    int*    cntA = (int*)(ws + 5 * UNITS * MAXN);          // 512 int
    float*  wns  = ws + 5 * UNITS * MAXN + UNITS;          // B*U
    float*  wds  = wns + BATCH * UNITS;                    // B*U
    float*  stA  = wds + BATCH * UNITS;                    // B*U
    float*  stB  = stA + BATCH * UNITS;                    // B*U

    prep_kernel<<<1024, 256, 0, stream>>>(
        inputs, input_w, input_b, ssig, smu, sw, serev, smask,
        sigma, mu, w, erev, mask, qvA, idxA, cntA, wns, wds);

    float* state_out = out + BATCH * MOTOR;  // next_state region of d_out
    float* dsts[UNFOLDS] = {stA, stB, stA, stB, stA, state_out};

    const float* src = state;
    for (int t = 0; t < UNFOLDS; ++t) {
        int last = (t == UNFOLDS - 1) ? 1 : 0;
        unfold_sparse_kernel<<<1024, 256, 0, stream>>>(
            src, dsts[t], qvA, idxA, cntA, wns, wds,
            gleak, vleak, cm, output_w, output_b, out, last);
        src = dsts[t];
    }
}

// Round 7
// 80.721 us; speedup vs baseline: 8.9153x; 1.0994x over previous
//
#include <hip/hip_runtime.h>

#define BATCH 128
#define SENS 128
#define UNITS 512
#define MOTOR 64
#define UNFOLDS 6
#define L2E 1.442695040888963f
#define EPS 1e-8f

#define BT 8      // batches per block (register-blocked)
#define UT 8      // units per block
#define STP 12    // transposed LDS row stride (8 data + 4 pad, conflict-free)

// ===========================================================================
// First unfold: fuses x-affine + sensory accumulators (written to wns/wds),
// on-the-fly weight fold (bt==0 blocks persist pw4 for later unfolds), and
// ODE unfold step 0.  1024 blocks x 256 threads.
// ===========================================================================
__global__ __launch_bounds__(256, 4) void unfold_first_kernel(
    const float* __restrict__ inputs, const float* __restrict__ state,
    const float* __restrict__ sigma, const float* __restrict__ mu,
    const float* __restrict__ w, const float* __restrict__ erev,
    const float* __restrict__ mask,
    const float* __restrict__ ssig, const float* __restrict__ smu,
    const float* __restrict__ sw, const float* __restrict__ serev,
    const float* __restrict__ smask,
    const float* __restrict__ input_w, const float* __restrict__ input_b,
    const float* __restrict__ gleak, const float* __restrict__ vleak,
    const float* __restrict__ cm,
    float4* __restrict__ pw4,
    float* __restrict__ wns, float* __restrict__ wds,
    float* __restrict__ dst)
{
    __shared__ __align__(16) float stT[UNITS][STP];  // state transposed [v][b]
    __shared__ __align__(16) float xsT[SENS][STP];   // x transposed [s][b]
    __shared__ float2 red[4][BT][UT];

    int tid = threadIdx.x;

    // block tile mapping (bijective XCD chunking: 1024 % 8 == 0)
    int logical = (blockIdx.x & 7) * 128 + (blockIdx.x >> 3);
    int ut = logical >> 4;                 // 0..63
    int bt = logical & 15;                 // 0..15
    int b0 = bt * BT;
    int u0 = ut * UT;

    int ul  = tid & 7;
    int grp = tid >> 3;                    // 0..31
    int u = u0 + ul;
    int lane = tid & 63;
    int wid = tid >> 6;

    // ---- stage state tile (transposed) and x tile (affine applied) ----
    {
        int bl = tid & 7;
        int v4b = tid >> 3;                // 0..31
        const float4* sv = (const float4*)(state + (size_t)b0 * UNITS);
        #pragma unroll
        for (int k = 0; k < 4; ++k) {
            int v4 = v4b + 32 * k;         // 0..127
            float4 t4 = sv[bl * (UNITS / 4) + v4];
            stT[v4 * 4 + 0][bl] = t4.x;
            stT[v4 * 4 + 1][bl] = t4.y;
            stT[v4 * 4 + 2][bl] = t4.z;
            stT[v4 * 4 + 3][bl] = t4.w;
        }
        const float4* xv = (const float4*)(inputs + (size_t)(b0 + bl) * SENS);
        float4 t4 = xv[v4b];
        float4 iw = ((const float4*)input_w)[v4b];
        float4 ib = ((const float4*)input_b)[v4b];
        xsT[v4b * 4 + 0][bl] = __builtin_fmaf(t4.x, iw.x, ib.x);
        xsT[v4b * 4 + 1][bl] = __builtin_fmaf(t4.y, iw.y, ib.y);
        xsT[v4b * 4 + 2][bl] = __builtin_fmaf(t4.z, iw.z, ib.z);
        xsT[v4b * 4 + 3][bl] = __builtin_fmaf(t4.w, iw.w, ib.w);
    }
    __syncthreads();

    // ---- sensory accumulators (raw weights, used once) ----
    float num[BT], den[BT];
    #pragma unroll
    for (int b = 0; b < BT; ++b) { num[b] = 0.f; den[b] = 0.f; }

    #pragma unroll
    for (int i = 0; i < SENS / 32; ++i) {  // s = grp + 32*i
        int s = grp + 32 * i;
        size_t k = (size_t)s * UNITS + u;
        float sgv = ssig[k] * L2E;
        float mt  = smu[k] * sgv;
        float wmv = sw[k] * smask[k];
        float wev = wmv * serev[k];
        const float4* sp = (const float4*)&xsT[s][0];
        float4 xa = sp[0];
        float4 xb = sp[1];
        float sarr[8] = {xa.x, xa.y, xa.z, xa.w, xb.x, xb.y, xb.z, xb.w};
        #pragma unroll
        for (int b = 0; b < BT; ++b) {
            float t = __builtin_fmaf(-sarr[b], sgv, mt);
            float e = __builtin_amdgcn_exp2f(t);
            float sg = __builtin_amdgcn_rcpf(1.0f + e);
            num[b] = __builtin_fmaf(wev, sg, num[b]);
            den[b] = __builtin_fmaf(wmv, sg, den[b]);
        }
    }
    #pragma unroll
    for (int b = 0; b < BT; ++b) {
        #pragma unroll
        for (int m = 8; m <= 32; m <<= 1) {
            num[b] += __shfl_xor(num[b], m, 64);
            den[b] += __shfl_xor(den[b], m, 64);
        }
    }
    if (lane < 8) {
        #pragma unroll
        for (int b = 0; b < BT; ++b)
            red[wid][b][lane] = make_float2(num[b], den[b]);
    }
    __syncthreads();
    float esn = 0.f, esd = 0.f;            // sensory sums (valid for tid<64)
    if (tid < 64) {
        int uu = tid & 7;
        int bb = tid >> 3;
        #pragma unroll
        for (int k = 0; k < 4; ++k) {
            float2 v = red[k][bb][uu];
            esn += v.x; esd += v.y;
        }
        int gidx = (b0 + bb) * UNITS + (u0 + uu);
        wns[gidx] = esn;                   // persist for unfolds 1..5
        wds[gidx] = esd;
    }
    __syncthreads();                       // red[] reused below

    // ---- recurrent accumulation, fold-on-the-fly; bt==0 persists pw4 ----
    #pragma unroll
    for (int b = 0; b < BT; ++b) { num[b] = 0.f; den[b] = 0.f; }

    #pragma unroll 4
    for (int i = 0; i < UNITS / 32; ++i) { // v = grp + 32*i
        int v = grp + 32 * i;
        size_t k = (size_t)v * UNITS + u;
        float sgv = sigma[k] * L2E;
        float wmv = w[k] * mask[k];
        float4 q;
        q.x = sgv; q.y = mu[k] * sgv; q.z = wmv; q.w = wmv * erev[k];
        if (bt == 0) pw4[k] = q;
        const float4* sp = (const float4*)&stT[v][0];
        float4 xa = sp[0];
        float4 xb = sp[1];
        float sarr[8] = {xa.x, xa.y, xa.z, xa.w, xb.x, xb.y, xb.z, xb.w};
        #pragma unroll
        for (int b = 0; b < BT; ++b) {
            float t = __builtin_fmaf(-sarr[b], q.x, q.y);
            float e = __builtin_amdgcn_exp2f(t);
            float sg = __builtin_amdgcn_rcpf(1.0f + e);
            num[b] = __builtin_fmaf(q.w, sg, num[b]);
            den[b] = __builtin_fmaf(q.z, sg, den[b]);
        }
    }
    #pragma unroll
    for (int b = 0; b < BT; ++b) {
        #pragma unroll
        for (int m = 8; m <= 32; m <<= 1) {
            num[b] += __shfl_xor(num[b], m, 64);
            den[b] += __shfl_xor(den[b], m, 64);
        }
    }
    if (lane < 8) {
        #pragma unroll
        for (int b = 0; b < BT; ++b)
            red[wid][b][lane] = make_float2(num[b], den[b]);
    }
    __syncthreads();
    if (tid < 64) {
        int uu = tid & 7;
        int bb = tid >> 3;
        float n = 0.f, d = 0.f;
        #pragma unroll
        for (int k = 0; k < 4; ++k) {
            float2 v = red[k][bb][uu];
            n += v.x; d += v.y;
        }
        int gu = u0 + uu;
        int gb = b0 + bb;
        float vpre = stT[gu][bb];
        float g = gleak[gu];
        float c = cm[gu] * (float)UNFOLDS;
        float numer = __builtin_fmaf(c, vpre,
                        __builtin_fmaf(g, vleak[gu], esn + n));
        float denom = c + g + esd + d + EPS;
        dst[gb * UNITS + gu] = numer * __builtin_amdgcn_rcpf(denom);
    }
}

// ===========================================================================
// Unfolds 1..5 (R3-proven): packed float4 weights, transposed LDS state,
// 8 batch-accumulators per thread, shfl + LDS reduce.
// ===========================================================================
__global__ __launch_bounds__(256, 4) void unfold_kernel(
    const float* __restrict__ src,
    float* __restrict__ dst,
    const float4* __restrict__ pw4,
    const float* __restrict__ wns, const float* __restrict__ wds,
    const float* __restrict__ gleak, const float* __restrict__ vleak,
    const float* __restrict__ cm,
    const float* __restrict__ output_w, const float* __restrict__ output_b,
    float* __restrict__ out_motor,
    int last)
{
    __shared__ __align__(16) float stT[UNITS][STP];
    __shared__ float2 red[4][BT][UT];

    int phys = blockIdx.x;
    int logical = (phys & 7) * 128 + (phys >> 3);
    int ut = logical >> 4;
    int bt = logical & 15;
    int b0 = bt * BT;
    int u0 = ut * UT;

    {
        const float4* sv = (const float4*)(src + (size_t)b0 * UNITS);
        int bl = threadIdx.x & 7;
        int v4b = threadIdx.x >> 3;
        #pragma unroll
        for (int k = 0; k < 4; ++k) {
            int v4 = v4b + 32 * k;
            float4 t = sv[bl * (UNITS / 4) + v4];
            stT[v4 * 4 + 0][bl] = t.x;
            stT[v4 * 4 + 1][bl] = t.y;
            stT[v4 * 4 + 2][bl] = t.z;
            stT[v4 * 4 + 3][bl] = t.w;
        }
    }
    __syncthreads();

    int ul = threadIdx.x & 7;
    int vs = threadIdx.x >> 3;
    int u = u0 + ul;

    float num[BT], den[BT];
    #pragma unroll
    for (int b = 0; b < BT; ++b) { num[b] = 0.f; den[b] = 0.f; }

    const float4* pv = pw4 + (size_t)vs * UNITS + u;
    const float* srow = &stT[vs][0];
    #pragma unroll 4
    for (int i = 0; i < UNITS / 32; ++i) {
        float4 q = pv[0];
        pv += 32 * UNITS;
        const float4* sp = (const float4*)srow;
        float4 xa = sp[0];
        float4 xb = sp[1];
        srow += 32 * STP;
        float sarr[8] = {xa.x, xa.y, xa.z, xa.w, xb.x, xb.y, xb.z, xb.w};
        #pragma unroll
        for (int b = 0; b < BT; ++b) {
            float t = __builtin_fmaf(-sarr[b], q.x, q.y);
            float e = __builtin_amdgcn_exp2f(t);
            float sg = __builtin_amdgcn_rcpf(1.0f + e);
            num[b] = __builtin_fmaf(q.w, sg, num[b]);
            den[b] = __builtin_fmaf(q.z, sg, den[b]);
        }
    }
    #pragma unroll
    for (int b = 0; b < BT; ++b) {
        #pragma unroll
        for (int m = 8; m <= 32; m <<= 1) {
            num[b] += __shfl_xor(num[b], m, 64);
            den[b] += __shfl_xor(den[b], m, 64);
        }
    }
    int lane = threadIdx.x & 63;
    int wid = threadIdx.x >> 6;
    if (lane < 8) {
        #pragma unroll
        for (int b = 0; b < BT; ++b)
            red[wid][b][lane] = make_float2(num[b], den[b]);
    }
    __syncthreads();
    if (threadIdx.x < 64) {
        int uu = threadIdx.x & 7;
        int bb = threadIdx.x >> 3;
        float n = 0.f, d = 0.f;
        #pragma unroll
        for (int k = 0; k < 4; ++k) {
            float2 v = red[k][bb][uu];
            n += v.x; d += v.y;
        }
        int gu = u0 + uu;
        int gb = b0 + bb;
        float vpre = stT[gu][bb];
        float g = gleak[gu];
        float c = cm[gu] * (float)UNFOLDS;
        int gidx = gb * UNITS + gu;
        float numer = __builtin_fmaf(c, vpre,
                        __builtin_fmaf(g, vleak[gu], wns[gidx] + n));
        float denom = c + g + wds[gidx] + d + EPS;
        float res = numer * __builtin_amdgcn_rcpf(denom);
        dst[gidx] = res;
        if (last && gu < MOTOR) {
            out_motor[gb * MOTOR + gu] =
                __builtin_fmaf(res, output_w[gu], output_b[gu]);
        }
    }
}

// ===========================================================================
extern "C" void kernel_launch(void* const* d_in, const int* in_sizes, int n_in,
                              void* d_out, int out_size, void* d_ws, size_t ws_size,
                              hipStream_t stream) {
    const float* inputs   = (const float*)d_in[0];
    const float* state    = (const float*)d_in[1];
    const float* gleak    = (const float*)d_in[2];
    const float* vleak    = (const float*)d_in[3];
    const float* cm       = (const float*)d_in[4];
    const float* sigma    = (const float*)d_in[5];
    const float* mu       = (const float*)d_in[6];
    const float* w        = (const float*)d_in[7];
    const float* erev     = (const float*)d_in[8];
    const float* ssig     = (const float*)d_in[9];
    const float* smu      = (const float*)d_in[10];
    const float* sw       = (const float*)d_in[11];
    const float* serev    = (const float*)d_in[12];
    const float* input_w  = (const float*)d_in[13];
    const float* input_b  = (const float*)d_in[14];
    const float* output_w = (const float*)d_in[15];
    const float* output_b = (const float*)d_in[16];
    const float* mask     = (const float*)d_in[17];
    const float* smask    = (const float*)d_in[18];

    float* out = (float*)d_out;
    float* ws  = (float*)d_ws;

    float4* pw4 = (float4*)ws;                 // U*U float4 (4 MB)
    float*  wns = ws + 4 * UNITS * UNITS;      // B*U
    float*  wds = wns + BATCH * UNITS;         // B*U
    float*  stA = wds + BATCH * UNITS;         // B*U
    float*  stB = stA + BATCH * UNITS;         // B*U

    // unfold 0: fused x-affine + sensory + fold + step
    unfold_first_kernel<<<1024, 256, 0, stream>>>(
        inputs, state, sigma, mu, w, erev, mask,
        ssig, smu, sw, serev, smask, input_w, input_b,
        gleak, vleak, cm, pw4, wns, wds, stA);

    // unfolds 1..5
    float* state_out = out + BATCH * MOTOR;
    float* dsts[5] = {stB, stA, stB, stA, state_out};
    const float* src = stA;
    for (int t = 0; t < 5; ++t) {
        int last = (t == 4) ? 1 : 0;
        unfold_kernel<<<1024, 256, 0, stream>>>(
            src, dsts[t], pw4, wns, wds,
            gleak, vleak, cm, output_w, output_b, out, last);
        src = dsts[t];
    }
}